// Round 8
// baseline (28.815 us; speedup 1.0000x reference)
//
#include <hip/hip_runtime.h>
#include <math.h>

#define B_N 8192
#define U_N 256
#define F_N 128
#define UG  32    // u's per block = 2 MFMA n-tiles
#define BT  128   // b-rows per block = 8 waves x 16

typedef __attribute__((ext_vector_type(8))) short short8;   // 8 bf16
typedef __attribute__((ext_vector_type(4))) float f32x4;    // MFMA C/D

static __device__ __forceinline__ unsigned short f2bf(float v) {
  union { float f; unsigned int u; } c; c.f = v;
  unsigned int r = c.u + 0x7fffu + ((c.u >> 16) & 1u);  // RNE
  return (unsigned short)(r >> 16);
}

// CALIBRATION BUILD: this is byte-for-byte the round-3 kernel (13.0 us total,
// absmax 0.0) -- the best so far. The ONLY change is in kernel_launch: the
// kernel is launched 3x (idempotent: rewrites the same output). Slope of
// dur_us vs launch count splits fixed graph/launch overhead from kernel time.
__global__ __launch_bounds__(512, 4) void bp_kernel(
    const float* __restrict__ x, const float* __restrict__ shift,
    const float* __restrict__ semi, const float* __restrict__ sharp,
    const float* __restrict__ mult, float* __restrict__ out) {
  __shared__ __align__(16) unsigned short Wf[2][8][64][8];  // 16 KB
  __shared__ float Cs[UG];

  const int tid   = threadIdx.x;
  const int lane  = tid & 63;
  const int w     = tid >> 6;
  const int lg    = lane >> 4;
  const int ln    = lane & 15;
  const int btile = blockIdx.x;
  const int u0    = blockIdx.y * UG;

  const int brow0 = btile * BT + w * 16;
  const float* xrow = x + (size_t)(brow0 + ln) * F_N;
  float4 xv[8];
#pragma unroll
  for (int s4 = 0; s4 < 4; ++s4) {
    xv[s4 * 2]     = *reinterpret_cast<const float4*>(xrow + s4 * 32 + lg * 8);
    xv[s4 * 2 + 1] = *reinterpret_cast<const float4*>(xrow + s4 * 32 + lg * 8 + 4);
  }

  {
    const int u_loc = tid >> 4;
    const int f0    = (tid & 15) * 8;
    const float* sp = shift + (size_t)(u0 + u_loc) * F_N + f0;
    const float* ap = semi  + (size_t)(u0 + u_loc) * F_N + f0;
    float4 s0 = *reinterpret_cast<const float4*>(sp);
    float4 s1 = *reinterpret_cast<const float4*>(sp + 4);
    float4 a0 = *reinterpret_cast<const float4*>(ap);
    float4 a1 = *reinterpret_cast<const float4*>(ap + 4);
    float ss[8] = {s0.x, s0.y, s0.z, s0.w, s1.x, s1.y, s1.z, s1.w};
    float aa[8] = {a0.x, a0.y, a0.z, a0.w, a1.x, a1.y, a1.z, a1.w};
    unsigned short qi[8], qb[8];
    float csum = 0.f;
#pragma unroll
    for (int j = 0; j < 8; ++j) {
      float inv = 1.0f / (aa[j] * aa[j]);
      qi[j] = f2bf(inv);
      qb[j] = f2bf(2.0f * ss[j] * inv);
      csum += ss[j] * ss[j] * inv;
    }
    const int tile = u_loc >> 4;
    const int kkp  = f0 >> 5;
    const int lnp  = ((f0 >> 3) & 3) * 16 + (u_loc & 15);
    *reinterpret_cast<uint2*>(&Wf[tile][kkp][lnp][0])     = *reinterpret_cast<uint2*>(qi);
    *reinterpret_cast<uint2*>(&Wf[tile][kkp][lnp][4])     = *reinterpret_cast<uint2*>(qi + 4);
    *reinterpret_cast<uint2*>(&Wf[tile][kkp + 4][lnp][0]) = *reinterpret_cast<uint2*>(qb);
    *reinterpret_cast<uint2*>(&Wf[tile][kkp + 4][lnp][4]) = *reinterpret_cast<uint2*>(qb + 4);
    csum += __shfl_xor(csum, 1, 64);
    csum += __shfl_xor(csum, 2, 64);
    csum += __shfl_xor(csum, 4, 64);
    csum += __shfl_xor(csum, 8, 64);
    if ((lane & 15) == 0) Cs[u_loc] = csum;
  }

  short8 fx2[4], fx1[4];
#pragma unroll
  for (int s4 = 0; s4 < 4; ++s4) {
    float xs[8] = {xv[s4*2].x, xv[s4*2].y, xv[s4*2].z, xv[s4*2].w,
                   xv[s4*2+1].x, xv[s4*2+1].y, xv[s4*2+1].z, xv[s4*2+1].w};
    short8 a2, a1;
#pragma unroll
    for (int j = 0; j < 8; ++j) {
      a2[j] = (short)f2bf(xs[j] * xs[j]);
      a1[j] = (short)f2bf(xs[j]);
    }
    fx2[s4] = a2; fx1[s4] = a1;
  }

  __syncthreads();

  f32x4 acc0 = {0.f, 0.f, 0.f, 0.f};
  f32x4 acc1 = {0.f, 0.f, 0.f, 0.f};
#pragma unroll
  for (int kk = 0; kk < 8; ++kk) {
    short8 a = (kk < 4) ? fx2[kk] : fx1[kk - 4];
    short8 b0 = *reinterpret_cast<const short8*>(&Wf[0][kk][lane][0]);
    short8 b1 = *reinterpret_cast<const short8*>(&Wf[1][kk][lane][0]);
    acc0 = __builtin_amdgcn_mfma_f32_16x16x32_bf16(a, b0, acc0, 0, 0, 0);
    acc1 = __builtin_amdgcn_mfma_f32_16x16x32_bf16(a, b1, acc1, 0, 0, 0);
  }

#pragma unroll
  for (int s = 0; s < 2; ++s) {
    f32x4 acc = s ? acc1 : acc0;
    const int u = u0 + s * 16 + ln;
    const float c  = Cs[s * 16 + ln];
    const float sh = sharp[u];
    const float mu = mult[u];
#pragma unroll
    for (int r = 0; r < 4; ++r) {
      const int b = brow0 + lg * 4 + r;
      float quad = acc[r] + c;
      float z = sh * (1.0f - quad);
      float e = __expf(-z);
      out[(size_t)b * U_N + u] = mu / (1.0f + e);
    }
  }
}

extern "C" void kernel_launch(void* const* d_in, const int* in_sizes, int n_in,
                              void* d_out, int out_size, void* d_ws, size_t ws_size,
                              hipStream_t stream) {
  (void)in_sizes; (void)n_in; (void)out_size; (void)d_ws; (void)ws_size;
  const float* x     = (const float*)d_in[0];
  const float* shift = (const float*)d_in[1];
  const float* semi  = (const float*)d_in[2];
  const float* sharp = (const float*)d_in[3];
  const float* mult  = (const float*)d_in[4];
  float* out = (float*)d_out;

  // 3 identical idempotent launches: dur = overhead + 3*k + 2*gap.
  // Against the single-launch baseline 13.0 us: k + gap = (dur - 13.0)/2.
  bp_kernel<<<dim3(B_N / BT, U_N / UG), 512, 0, stream>>>(x, shift, semi, sharp, mult, out);
  bp_kernel<<<dim3(B_N / BT, U_N / UG), 512, 0, stream>>>(x, shift, semi, sharp, mult, out);
  bp_kernel<<<dim3(B_N / BT, U_N / UG), 512, 0, stream>>>(x, shift, semi, sharp, mult, out);
}

// Round 9
// 15.552 us; speedup vs baseline: 1.8528x; 1.8528x over previous
//
#include <hip/hip_runtime.h>
#include <hip/hip_bf16.h>
#include <math.h>

#define B_N 8192
#define U_N 256
#define F_N 128
#define UG  16    // u's per block (1 MFMA n-tile; prep = exactly one 256-thr pass)
#define BT  64    // b-rows per iteration (4 waves x 16)
#define NITER 2   // b-tiles per block -> block covers 128 rows

typedef __attribute__((ext_vector_type(8))) short short8;   // 8 bf16
typedef __attribute__((ext_vector_type(4))) float f32x4;    // MFMA C/D

static __device__ __forceinline__ unsigned short f2bf(float v) {
  __hip_bfloat16 h = __float2bfloat16(v);
  return *reinterpret_cast<unsigned short*>(&h);
}

static __device__ __forceinline__ short8 pack8(const float4& a, const float4& b, bool sq) {
  float xs[8] = {a.x, a.y, a.z, a.w, b.x, b.y, b.z, b.w};
  short8 r;
#pragma unroll
  for (int j = 0; j < 8; ++j) {
    float v = sq ? xs[j] * xs[j] : xs[j];
    r[j] = (short)f2bf(v);
  }
  return r;
}

// Fused. Block = 16 u's x (2 x 64 b-rows). Prep once -> barrier -> 2 barrier-free
// streaming iterations (load x -> cvt -> 8 MFMA -> sigmoid -> float4 store).
__global__ __launch_bounds__(256, 4) void bp_kernel(
    const float* __restrict__ x, const float* __restrict__ shift,
    const float* __restrict__ semi, const float* __restrict__ sharp,
    const float* __restrict__ mult, float* __restrict__ out) {
  // Wf[kk][lane][j] = W[u0+(lane&15)][kk*32+(lane>>4)*8+j]; W = [1/sa^2 | 2s/sa^2]
  __shared__ __align__(16) unsigned short Wf[8][64][8];   // 8 KB
  __shared__ float Cs[UG];

  const int tid  = threadIdx.x;
  const int lane = tid & 63;
  const int w    = tid >> 6;     // wave 0..3
  const int lg   = lane >> 4;    // 0..3
  const int ln   = lane & 15;    // 0..15
  const int u0   = blockIdx.y * UG;
  const int bbase = blockIdx.x * (BT * NITER);

  // ---- issue iter-0 x loads first (overlap prep latency) ----
  const float* xrow0 = x + (size_t)(bbase + w * 16 + ln) * F_N;
  float4 xa[4], xb[4];
#pragma unroll
  for (int s4 = 0; s4 < 4; ++s4) {
    xa[s4] = *reinterpret_cast<const float4*>(xrow0 + s4 * 32 + lg * 8);
    xb[s4] = *reinterpret_cast<const float4*>(xrow0 + s4 * 32 + lg * 8 + 4);
  }

  // ---- prep: one pass, 16 u x 16 f-chunks = 256 threads ----
  {
    const int u_loc = tid >> 4;        // 0..15
    const int f0    = (tid & 15) * 8;  // 0..120
    const float* sp = shift + (size_t)(u0 + u_loc) * F_N + f0;
    const float* ap = semi  + (size_t)(u0 + u_loc) * F_N + f0;
    float4 s0 = *reinterpret_cast<const float4*>(sp);
    float4 s1 = *reinterpret_cast<const float4*>(sp + 4);
    float4 a0 = *reinterpret_cast<const float4*>(ap);
    float4 a1 = *reinterpret_cast<const float4*>(ap + 4);
    float ss[8] = {s0.x, s0.y, s0.z, s0.w, s1.x, s1.y, s1.z, s1.w};
    float aa[8] = {a0.x, a0.y, a0.z, a0.w, a1.x, a1.y, a1.z, a1.w};
    unsigned short qi[8], qb[8];
    float csum = 0.f;
#pragma unroll
    for (int j = 0; j < 8; ++j) {
      float inv = __builtin_amdgcn_rcpf(aa[j] * aa[j]);
      qi[j] = f2bf(inv);
      qb[j] = f2bf(2.0f * ss[j] * inv);
      csum += ss[j] * ss[j] * inv;
    }
    const int kkp = f0 >> 5;                       // 0..3
    const int lnp = ((f0 >> 3) & 3) * 16 + u_loc;  // fragment lane
    *reinterpret_cast<uint2*>(&Wf[kkp][lnp][0])     = *reinterpret_cast<uint2*>(qi);
    *reinterpret_cast<uint2*>(&Wf[kkp][lnp][4])     = *reinterpret_cast<uint2*>(qi + 4);
    *reinterpret_cast<uint2*>(&Wf[kkp + 4][lnp][0]) = *reinterpret_cast<uint2*>(qb);
    *reinterpret_cast<uint2*>(&Wf[kkp + 4][lnp][4]) = *reinterpret_cast<uint2*>(qb + 4);
    csum += __shfl_xor(csum, 1, 64);
    csum += __shfl_xor(csum, 2, 64);
    csum += __shfl_xor(csum, 4, 64);
    csum += __shfl_xor(csum, 8, 64);
    if ((tid & 15) == 0) Cs[u_loc] = csum;
  }

  // per-u epilogue params (thread owns u = u0 + lg*4 + 0..3)
  const float4 sh4 = *reinterpret_cast<const float4*>(&sharp[u0 + lg * 4]);
  const float4 mu4 = *reinterpret_cast<const float4*>(&mult[u0 + lg * 4]);
  const float shs[4] = {sh4.x, sh4.y, sh4.z, sh4.w};
  const float mus[4] = {mu4.x, mu4.y, mu4.z, mu4.w};

  __syncthreads();

  const float4 c4 = *reinterpret_cast<const float4*>(&Cs[lg * 4]);
  const float cc[4] = {c4.x, c4.y, c4.z, c4.w};

  // ---- issue iter-1 x loads now: they fill latency under iter-0 compute ----
  const float* xrow1 = xrow0 + (size_t)BT * F_N;
  float4 ya[4], yb[4];
#pragma unroll
  for (int s4 = 0; s4 < 4; ++s4) {
    ya[s4] = *reinterpret_cast<const float4*>(xrow1 + s4 * 32 + lg * 8);
    yb[s4] = *reinterpret_cast<const float4*>(xrow1 + s4 * 32 + lg * 8 + 4);
  }

#pragma unroll
  for (int it = 0; it < NITER; ++it) {
    const int brow = bbase + it * BT + w * 16 + ln;

    // pack x fragments: kk<4 -> x^2 chunk kk ; kk>=4 -> x chunk kk-4
    short8 fx[8];
#pragma unroll
    for (int s4 = 0; s4 < 4; ++s4) {
      const float4 a = it ? ya[s4] : xa[s4];
      const float4 b = it ? yb[s4] : xb[s4];
      fx[s4]     = pack8(a, b, true);
      fx[s4 + 4] = pack8(a, b, false);
    }

    // GEMM: K=256, 8 MFMAs; W as A-operand from LDS (fragment-linear ds_read_b128)
    f32x4 acc = {0.f, 0.f, 0.f, 0.f};
#pragma unroll
    for (int kk = 0; kk < 8; ++kk) {
      short8 wv = *reinterpret_cast<const short8*>(&Wf[kk][lane][0]);
      acc = __builtin_amdgcn_mfma_f32_16x16x32_bf16(wv, fx[kk], acc, 0, 0, 0);
    }

    // epilogue: D[row=u][col=b]; thread stores u-contiguous float4
    float res[4];
#pragma unroll
    for (int r = 0; r < 4; ++r) {
      float quad = acc[r] + cc[r];
      float e = __expf(shs[r] * (quad - 1.0f));           // = exp(-z); inf when saturated
      res[r] = mus[r] * __builtin_amdgcn_rcpf(1.0f + e);  // rcp(inf)=+0 -> +-0
    }
    *reinterpret_cast<float4*>(&out[(size_t)brow * U_N + u0 + lg * 4]) =
        make_float4(res[0], res[1], res[2], res[3]);
  }
}

extern "C" void kernel_launch(void* const* d_in, const int* in_sizes, int n_in,
                              void* d_out, int out_size, void* d_ws, size_t ws_size,
                              hipStream_t stream) {
  (void)in_sizes; (void)n_in; (void)out_size; (void)d_ws; (void)ws_size;
  const float* x     = (const float*)d_in[0];
  const float* shift = (const float*)d_in[1];
  const float* semi  = (const float*)d_in[2];
  const float* sharp = (const float*)d_in[3];
  const float* mult  = (const float*)d_in[4];
  float* out = (float*)d_out;

  bp_kernel<<<dim3(B_N / (BT * NITER), U_N / UG), 256, 0, stream>>>(
      x, shift, semi, sharp, mult, out);
}

// Round 10
// 11.616 us; speedup vs baseline: 2.4807x; 1.3389x over previous
//
#include <hip/hip_runtime.h>
#include <hip/hip_bf16.h>
#include <math.h>

#define B_N 8192
#define U_N 256
#define F_N 128
#define UG  32    // u's per block = 2 MFMA n-tiles
#define BT  128   // b-rows per block = 8 waves x 16

typedef __attribute__((ext_vector_type(8))) short short8;   // 8 bf16
typedef __attribute__((ext_vector_type(4))) float f32x4;    // MFMA C/D

static __device__ __forceinline__ unsigned short f2bf(float v) {
  __hip_bfloat16 h = __float2bfloat16(v);
  return *reinterpret_cast<unsigned short*>(&h);
}

// Physical byte offsets with XOR swizzle (write and read use the same map).
// Wf logical: [tile<2][kk<8][lane<64][j<8] bf16 ; slot = 16 B
static __device__ __forceinline__ int wf_off(int tile, int kk, int lane) {
  return tile * 8192 + kk * 1024 + ((lane * 16) ^ ((kk & 3) << 5));
}
// Bfx logical: [tl<8][kk<4][lane<64][j<8] bf16 (x-half fragments only)
static __device__ __forceinline__ int bf_off(int tl, int kk, int lane) {
  return tl * 4096 + kk * 1024 + ((lane * 16) ^ (kk << 5));
}

// One fused kernel, R3 tile shape (512 thr, 32 u x 128 b), but ALL global
// accesses lane-contiguous; fragments go through swizzled LDS.
__global__ __launch_bounds__(512, 4) void bp_kernel(
    const float* __restrict__ x, const float* __restrict__ shift,
    const float* __restrict__ semi, const float* __restrict__ sharp,
    const float* __restrict__ mult, float* __restrict__ out) {
  __shared__ __align__(16) short Wf[2 * 8 * 64 * 8];    // 16 KB
  __shared__ __align__(16) short Bfx[8 * 4 * 64 * 8];   // 32 KB
  __shared__ __align__(16) float Cs[UG];

  const int tid  = threadIdx.x;
  const int l    = tid & 63;
  const int w    = tid >> 6;          // wave 0..7 -> owns b-rows w*16..+15
  const int u0   = blockIdx.y * UG;
  const int bbase = blockIdx.x * BT;

  // ---- 1) issue x loads: wave-local rows, lane-contiguous float4 ----
  const int xr_half = l >> 5;         // 0/1: which of the 2 rows this pass
  const int xf      = (l & 31) * 4;   // f-quad base 0..124
  float4 xl[8];
#pragma unroll
  for (int p = 0; p < 8; ++p) {
    const int row = bbase + w * 16 + p * 2 + xr_half;
    xl[p] = *reinterpret_cast<const float4*>(x + (size_t)row * F_N + xf);
  }

  // ---- 2) issue prep loads: flat lane-contiguous float4 ----
  const int pu = tid >> 5;            // 0..15 (u within half-group)
  const int pf = (tid & 31) * 4;      // f-quad 0..124
  float4 shf[2], sem[2];
#pragma unroll
  for (int q = 0; q < 2; ++q) {
    shf[q] = *reinterpret_cast<const float4*>(shift + (size_t)(u0 + pu + q * 16) * F_N + pf);
    sem[q] = *reinterpret_cast<const float4*>(semi  + (size_t)(u0 + pu + q * 16) * F_N + pf);
  }

  // ---- 3) prep compute: W fragments (bf16, swizzled) + Cs ----
  const int kkq = pf >> 5;                       // 0..3
  const int lnq = ((pf >> 3) & 3) * 16 + pu;     // fragment lane
  const int j0q = pf & 7;                        // 0 or 4
#pragma unroll
  for (int q = 0; q < 2; ++q) {
    const float ssv[4] = {shf[q].x, shf[q].y, shf[q].z, shf[q].w};
    const float aav[4] = {sem[q].x, sem[q].y, sem[q].z, sem[q].w};
    unsigned short qi[4], qb[4];
    float csum = 0.f;
#pragma unroll
    for (int j = 0; j < 4; ++j) {
      float inv = __builtin_amdgcn_rcpf(aav[j] * aav[j]);
      qi[j] = f2bf(inv);
      qb[j] = f2bf(2.0f * ssv[j] * inv);
      csum += ssv[j] * ssv[j] * inv;
    }
    char* wfb = reinterpret_cast<char*>(Wf);
    *reinterpret_cast<uint2*>(wfb + wf_off(q, kkq,     lnq) + j0q * 2) = *reinterpret_cast<uint2*>(qi);
    *reinterpret_cast<uint2*>(wfb + wf_off(q, kkq + 4, lnq) + j0q * 2) = *reinterpret_cast<uint2*>(qb);
    csum += __shfl_xor(csum, 1, 64);
    csum += __shfl_xor(csum, 2, 64);
    csum += __shfl_xor(csum, 4, 64);
    csum += __shfl_xor(csum, 8, 64);
    csum += __shfl_xor(csum, 16, 64);
    if ((tid & 31) == 0) Cs[pu + q * 16] = csum;
  }

  // ---- 4) x -> bf16 fragments into Bfx (wave-local tile, swizzled) ----
  const int bkk = (l & 31) >> 3;        // kk 0..3 (physical k = 128 + f)
  const int blg = ((l & 31) >> 1) & 3;  // k-group within fragment
  const int bj0 = (l & 1) * 4;          // j half
#pragma unroll
  for (int p = 0; p < 8; ++p) {
    const int rt   = p * 2 + xr_half;
    const int lane = blg * 16 + rt;
    unsigned short q4[4] = {f2bf(xl[p].x), f2bf(xl[p].y), f2bf(xl[p].z), f2bf(xl[p].w)};
    *reinterpret_cast<uint2*>(reinterpret_cast<char*>(Bfx) + bf_off(w, bkk, lane) + bj0 * 2) =
        *reinterpret_cast<uint2*>(q4);
  }

  __syncthreads();

  // ---- 5) fragments from LDS; x^2 frags computed in-register ----
  short8 bx[4], bx2[4];
#pragma unroll
  for (int k4 = 0; k4 < 4; ++k4)
    bx[k4] = *reinterpret_cast<const short8*>(
        reinterpret_cast<const char*>(Bfx) + bf_off(w, k4, l));
#pragma unroll
  for (int k4 = 0; k4 < 4; ++k4) {
    short8 o;
#pragma unroll
    for (int j = 0; j < 8; ++j) {
      const float f = __uint_as_float(((unsigned)(unsigned short)bx[k4][j]) << 16);
      o[j] = (short)f2bf(f * f);
    }
    bx2[k4] = o;
  }

  // ---- 6) GEMM: K=256, 16 MFMAs; W as A-operand -> D[row=u][col=b] ----
  f32x4 acc0 = {0.f, 0.f, 0.f, 0.f};
  f32x4 acc1 = {0.f, 0.f, 0.f, 0.f};
  const char* wfb = reinterpret_cast<const char*>(Wf);
#pragma unroll
  for (int kk = 0; kk < 8; ++kk) {
    const short8 b  = (kk < 4) ? bx2[kk] : bx[kk - 4];
    const short8 a0 = *reinterpret_cast<const short8*>(wfb + wf_off(0, kk, l));
    const short8 a1 = *reinterpret_cast<const short8*>(wfb + wf_off(1, kk, l));
    acc0 = __builtin_amdgcn_mfma_f32_16x16x32_bf16(a0, b, acc0, 0, 0, 0);
    acc1 = __builtin_amdgcn_mfma_f32_16x16x32_bf16(a1, b, acc1, 0, 0, 0);
  }

  // ---- 7) epilogue: thread owns b = bbase + w*16 + ln, u = u0+t*16+lg*4+r ----
  const int lg = l >> 4;
  const int ln = l & 15;
  const int brow = bbase + w * 16 + ln;
#pragma unroll
  for (int t = 0; t < 2; ++t) {
    const f32x4 acc = t ? acc1 : acc0;
    const int ub = t * 16 + lg * 4;
    const float4 c4  = *reinterpret_cast<const float4*>(&Cs[ub]);
    const float4 sh4 = *reinterpret_cast<const float4*>(&sharp[u0 + ub]);
    const float4 mu4 = *reinterpret_cast<const float4*>(&mult[u0 + ub]);
    const float cc[4]  = {c4.x, c4.y, c4.z, c4.w};
    const float shs[4] = {sh4.x, sh4.y, sh4.z, sh4.w};
    const float mus[4] = {mu4.x, mu4.y, mu4.z, mu4.w};
    float res[4];
#pragma unroll
    for (int r = 0; r < 4; ++r) {
      const float quad = acc[r] + cc[r];
      const float e = __expf(shs[r] * (quad - 1.0f));     // = exp(-z); inf when saturated
      res[r] = mus[r] * __builtin_amdgcn_rcpf(1.0f + e);  // rcp(inf)=+0 -> +-0
    }
    *reinterpret_cast<float4*>(&out[(size_t)brow * U_N + u0 + ub]) =
        make_float4(res[0], res[1], res[2], res[3]);
  }
}

extern "C" void kernel_launch(void* const* d_in, const int* in_sizes, int n_in,
                              void* d_out, int out_size, void* d_ws, size_t ws_size,
                              hipStream_t stream) {
  (void)in_sizes; (void)n_in; (void)out_size; (void)d_ws; (void)ws_size;
  const float* x     = (const float*)d_in[0];
  const float* shift = (const float*)d_in[1];
  const float* semi  = (const float*)d_in[2];
  const float* sharp = (const float*)d_in[3];
  const float* mult  = (const float*)d_in[4];
  float* out = (float*)d_out;

  bp_kernel<<<dim3(B_N / BT, U_N / UG), 512, 0, stream>>>(x, shift, semi, sharp, mult, out);
}